// Round 5
// baseline (13909.541 us; speedup 1.0000x reference)
//
#include <hip/hip_runtime.h>
#include <hip/hip_bf16.h>
#include <cstdint>
#include <cstddef>

#define B_ 8
#define S_ 4096
#define D_ 1024
#define SD_ (S_ * D_)

typedef float v2f __attribute__((ext_vector_type(2)));

// ============================================================================
// Phase 1: z[m][n] = sum_k x[m][k]*W_in[n][k] + b_in[n],  m in [0,32768), n in [0,2048)
//   n <  1024 : gates = sigmoid(z) -> d_out[m*1024 + n]            ([B][S][D] flat)
//   n >= 1024 : p = z              -> ws_p[(s*8 + b)*1024 + n-1024] (time-major,
//               f32 or bf16 per p_bf16 mode)
// 128x128x16 tile, 256 threads, 8x8 microtile (float2-packed FMAs),
// register-prefetch pipeline.  [verified r3/r4: ~1.7 ms]
// ============================================================================
__launch_bounds__(256, 2)
__global__ void gemm_in_kernel(const float* __restrict__ x, const float* __restrict__ w,
                               const float* __restrict__ bias, float* __restrict__ outg,
                               void* __restrict__ wsp, int p_bf16)
{
    __shared__ float As[16][132];   // [k][m], +4 pad: 16B-aligned b128 reads, <=2-way banks
    __shared__ float Bs[16][132];   // [k][n]
    const int tid = threadIdx.x;
    const int m0 = blockIdx.y * 128;
    const int n0 = blockIdx.x * 128;
    const int tx = tid & 15;        // n-direction
    const int ty = tid >> 4;        // m-direction
    const int r  = tid >> 2;        // staging row 0..63
    const int kq = tid & 3;         // staging k-quad 0..3

    v2f acc2[8][4];                 // [i][jj2] -> columns jj2*2, jj2*2+1
    #pragma unroll
    for (int i = 0; i < 8; ++i)
        #pragma unroll
        for (int j = 0; j < 4; ++j) acc2[i][j] = (v2f){0.f, 0.f};

    const float* ax = x + (size_t)(m0 + r) * D_ + kq * 4;
    const float* bx = w + (size_t)(n0 + r) * D_ + kq * 4;

    // prologue: prefetch tile 0 into registers
    float4 a0 = *(const float4*)(ax);
    float4 a1 = *(const float4*)(ax + (size_t)64 * D_);
    float4 b0 = *(const float4*)(bx);
    float4 b1 = *(const float4*)(bx + (size_t)64 * D_);

    for (int kt = 0; kt < 64; ++kt) {
        __syncthreads();  // previous iter's compute done before LDS overwrite
        As[kq*4+0][r]    = a0.x; As[kq*4+1][r]    = a0.y; As[kq*4+2][r]    = a0.z; As[kq*4+3][r]    = a0.w;
        As[kq*4+0][r+64] = a1.x; As[kq*4+1][r+64] = a1.y; As[kq*4+2][r+64] = a1.z; As[kq*4+3][r+64] = a1.w;
        Bs[kq*4+0][r]    = b0.x; Bs[kq*4+1][r]    = b0.y; Bs[kq*4+2][r]    = b0.z; Bs[kq*4+3][r]    = b0.w;
        Bs[kq*4+0][r+64] = b1.x; Bs[kq*4+1][r+64] = b1.y; Bs[kq*4+2][r+64] = b1.z; Bs[kq*4+3][r+64] = b1.w;
        __syncthreads();

        // issue next tile's loads NOW; they drain while we compute this tile
        const int k0n = (kt < 63 ? kt + 1 : 63) * 16;
        a0 = *(const float4*)(ax + k0n);
        a1 = *(const float4*)(ax + (size_t)64 * D_ + k0n);
        b0 = *(const float4*)(bx + k0n);
        b1 = *(const float4*)(bx + (size_t)64 * D_ + k0n);

        #pragma unroll
        for (int j = 0; j < 16; ++j) {
            float4 a0v = *(const float4*)&As[j][ty*4];
            float4 a1v = *(const float4*)&As[j][64 + ty*4];
            float4 b0v = *(const float4*)&Bs[j][tx*4];
            float4 b1v = *(const float4*)&Bs[j][64 + tx*4];
            float am[8] = {a0v.x,a0v.y,a0v.z,a0v.w,a1v.x,a1v.y,a1v.z,a1v.w};
            v2f bn2[4];
            bn2[0] = (v2f){b0v.x, b0v.y}; bn2[1] = (v2f){b0v.z, b0v.w};
            bn2[2] = (v2f){b1v.x, b1v.y}; bn2[3] = (v2f){b1v.z, b1v.w};
            #pragma unroll
            for (int i = 0; i < 8; ++i) {
                v2f as = (v2f){am[i], am[i]};
                #pragma unroll
                for (int jj = 0; jj < 4; ++jj)
                    acc2[i][jj] = __builtin_elementwise_fma(as, bn2[jj], acc2[i][jj]);
            }
        }
    }

    const int mloc[2] = {ty * 4, 64 + ty * 4};
    const int nloc[2] = {tx * 4, 64 + tx * 4};
    #pragma unroll
    for (int mh = 0; mh < 2; ++mh) {
        #pragma unroll
        for (int i = 0; i < 4; ++i) {
            const int m  = m0 + mloc[mh] + i;
            const int bb = m >> 12;       // batch
            const int ss = m & 4095;      // timestep
            #pragma unroll
            for (int nh = 0; nh < 2; ++nh) {
                const int nc = n0 + nloc[nh];
                float4 v;
                v.x = acc2[mh*4+i][nh*2+0][0] + bias[nc+0];
                v.y = acc2[mh*4+i][nh*2+0][1] + bias[nc+1];
                v.z = acc2[mh*4+i][nh*2+1][0] + bias[nc+2];
                v.w = acc2[mh*4+i][nh*2+1][1] + bias[nc+3];
                if (nc < D_) {
                    v.x = 1.f / (1.f + __expf(-v.x));
                    v.y = 1.f / (1.f + __expf(-v.y));
                    v.z = 1.f / (1.f + __expf(-v.z));
                    v.w = 1.f / (1.f + __expf(-v.w));
                    *(float4*)(outg + (size_t)m * D_ + nc) = v;            // gates -> d_out
                } else {
                    const size_t off = ((size_t)ss * B_ + bb) * D_ + (nc - D_);
                    if (!p_bf16) {
                        *(float4*)((float*)wsp + off) = v;                 // p f32 -> ws
                    } else {
                        union { __hip_bfloat16 h[4]; uint2 u; } pk;
                        pk.h[0] = __float2bfloat16(v.x); pk.h[1] = __float2bfloat16(v.y);
                        pk.h[2] = __float2bfloat16(v.z); pk.h[3] = __float2bfloat16(v.w);
                        *(uint2*)((__hip_bfloat16*)wsp + off) = pk.u;      // p bf16 -> ws
                    }
                }
            }
        }
    }
}

// ============================================================================
// Phase 2: persistent gated-RNN scan with SELF-VALIDATING TAGGED STATE.
//
// r5 redesign (r4 counters: 2.57us/step = ~6200cy = ~4 serialized LLC RTs):
//   State element = 64-bit word (f32 value | u32 tag=step). Published with ONE
//   relaxed agent-scope 8B store (single-copy atomic). Consumers poll exactly
//   the words they need: the load that sees tag==t ALSO delivers the value.
//   -> detect+stage fused into one LLC round trip; publish needs no vmcnt
//      drain and no flag; zero fences in the whole protocol.
//   Double-buffer safety: block enters step t+2's publish only after polling
//   ALL of s_{t+1}, which requires every block published s_{t+1}, which
//   requires every block done reading s_t. So buf[t&1] is never overwritten
//   while a straggler still reads s_t.
//   Barriers/step: C (part[] ready), D (part[] consumed before next overwrite;
//   needed because polls no longer gate on the own block's publish).
// ============================================================================
__launch_bounds__(256, 1)
__global__ void scan_kernel(const float* __restrict__ Ws, const float* __restrict__ bvec,
                            const void* __restrict__ wsp, float* __restrict__ outg,
                            unsigned long long* __restrict__ state64, // [2][8][1024] (value,tag), zeroed
                            unsigned* __restrict__ abortf,            // zeroed
                            int p_bf16)
{
    const int bid   = blockIdx.x;
    const int batch = bid >> 5;
    const int slice = bid & 31;
    const int tid   = threadIdx.x;
    const int rg    = tid & 3;        // row sub-group (8 rows each)
    const int kg    = tid >> 2;       // k-group 0..63 (16 k's each)
    const int wv    = tid >> 6;       // wave 0..3
    const int lane  = tid & 63;

    __shared__ float part[4 * 32];    // cross-wave partials [wave][row]
    __shared__ unsigned sab;

    // --- W_s slice -> registers (one-time) ---
    float wreg[8][16];
    const int k0 = kg * 16;
    #pragma unroll
    for (int rr = 0; rr < 8; ++rr) {
        const float* wp = Ws + (size_t)(slice * 32 + rg * 8 + rr) * D_ + k0;
        float4 w0 = *(const float4*)(wp + 0);
        float4 w1 = *(const float4*)(wp + 4);
        float4 w2 = *(const float4*)(wp + 8);
        float4 w3 = *(const float4*)(wp + 12);
        wreg[rr][0]=w0.x; wreg[rr][1]=w0.y; wreg[rr][2]=w0.z; wreg[rr][3]=w0.w;
        wreg[rr][4]=w1.x; wreg[rr][5]=w1.y; wreg[rr][6]=w1.z; wreg[rr][7]=w1.w;
        wreg[rr][8]=w2.x; wreg[rr][9]=w2.y; wreg[rr][10]=w2.z; wreg[rr][11]=w2.w;
        wreg[rr][12]=w3.x; wreg[rr][13]=w3.y; wreg[rr][14]=w3.z; wreg[rr][15]=w3.w;
    }

    const int grow = slice * 32 + tid;         // epilogue row (valid for tid<32)
    const bool epi = (tid < 32);
    float my_bs = 0.f;
    if (epi) my_bs = bvec[grow];
    if (tid == 0) sab = 0u;
    __syncthreads();                           // sab visible to all

    for (int t = 0; t < S_; ++t) {
        // ---- hoisted epilogue loads: issue before the poll, drain under it ----
        float gv = 0.f, pv = 0.f;
        size_t gidx = 0;
        if (epi) {
            gidx = (size_t)batch * SD_ + (size_t)t * D_ + grow;
            gv = outg[gidx];                                  // gate (read before overwrite)
            const size_t poff = ((size_t)t * B_ + batch) * D_ + grow;
            pv = p_bf16 ? __bfloat162float(((const __hip_bfloat16*)wsp)[poff])
                        : ((const float*)wsp)[poff];
        }

        // ---- tagged poll: my 16 k-words (+1 sold word for epi lanes) ----
        const unsigned long long* base =
            state64 + (size_t)(((t & 1) * B_) + batch) * D_;
        const unsigned want = (unsigned)t;

        unsigned long long wv_[16];
        unsigned long long sw = 0;
        bool dead = false;
        int spins = 0;
        while (true) {
            #pragma unroll
            for (int j = 0; j < 16; ++j)
                wv_[j] = __hip_atomic_load(base + k0 + j, __ATOMIC_RELAXED, __HIP_MEMORY_SCOPE_AGENT);
            if (epi)
                sw = __hip_atomic_load(base + grow, __ATOMIC_RELAXED, __HIP_MEMORY_SCOPE_AGENT);
            bool ok = true;
            #pragma unroll
            for (int j = 0; j < 16; ++j)
                ok = ok && ((unsigned)(wv_[j] >> 32) == want);
            if (epi) ok = ok && ((unsigned)(sw >> 32) == want);
            if (ok) break;
            ++spins;
            if ((spins & 31) == 0 &&
                __hip_atomic_load(abortf, __ATOMIC_RELAXED, __HIP_MEMORY_SCOPE_AGENT) != 0u) {
                dead = true; break;
            }
            if (spins > 60000) {
                __hip_atomic_store(abortf, 1u, __ATOMIC_RELAXED, __HIP_MEMORY_SCOPE_AGENT);
                dead = true; break;
            }
            __builtin_amdgcn_s_sleep(1);
        }
        if (dead) sab = 1u;    // any lane may set; checked after barrier C

        // ---- matvec: values came with the poll ----
        float sreg[16];
        #pragma unroll
        for (int j = 0; j < 16; ++j) sreg[j] = __uint_as_float((unsigned)wv_[j]);

        float acc[8];
        #pragma unroll
        for (int rr = 0; rr < 8; ++rr) acc[rr] = 0.f;
        #pragma unroll
        for (int j = 0; j < 16; ++j)
            #pragma unroll
            for (int rr = 0; rr < 8; ++rr)
                acc[rr] = fmaf(wreg[rr][j], sreg[j], acc[rr]);

        // reduce over kg within wave (lane bits 2..5)
        #pragma unroll
        for (int m = 4; m < 64; m <<= 1)
            #pragma unroll
            for (int rr = 0; rr < 8; ++rr)
                acc[rr] += __shfl_xor(acc[rr], m, 64);

        if (lane < 4) {           // lanes 0..3 hold wave-partials for rg = lane
            #pragma unroll
            for (int rr = 0; rr < 8; ++rr) part[wv * 32 + lane * 8 + rr] = acc[rr];
        }
        __syncthreads();          // (C) partials ready
        if (sab) return;          // uniform abort exit (validation fails loudly)

        // ---- epilogue + tagged publish (wave 0, lanes 0..31) ----
        if (epi) {
            float dot  = part[tid] + part[32 + tid] + part[64 + tid] + part[96 + tid];
            float sold = __uint_as_float((unsigned)sw);        // from the polled word
            float mix  = dot + my_bs + pv;
            float ns   = gv * mix + (1.f - gv) * sold;
            unsigned long long pub =
                ((unsigned long long)(unsigned)(t + 1) << 32) |
                (unsigned long long)__float_as_uint(ns);
            __hip_atomic_store(state64 + (size_t)((((t + 1) & 1) * B_) + batch) * D_ + grow,
                               pub, __ATOMIC_RELAXED, __HIP_MEMORY_SCOPE_AGENT);
            outg[gidx] = ns;                                   // off the unblock path
        }
        __syncthreads();          // (D) part[] consumed before next step overwrites
    }
}

// ============================================================================
extern "C" void kernel_launch(void* const* d_in, const int* in_sizes, int n_in,
                              void* d_out, int out_size, void* d_ws, size_t ws_size,
                              hipStream_t stream)
{
    const float* x    = (const float*)d_in[0];
    const float* W_in = (const float*)d_in[1];
    const float* b_in = (const float*)d_in[2];
    const float* W_s  = (const float*)d_in[3];
    const float* b_s  = (const float*)d_in[4];
    float* out = (float*)d_out;
    char*  ws  = (char*)d_ws;

    const size_t P_F32    = (size_t)S_ * B_ * D_ * 4;   // 134,217,728
    const size_t P_BF16   = (size_t)S_ * B_ * D_ * 2;   //  67,108,864
    const size_t STATE_B  = 2 * B_ * D_ * 8;            // 131,072 (tagged 64b words)
    const size_t TAIL     = STATE_B + 256;

    int p_bf16;
    size_t pbytes;
    if (ws_size >= P_F32 + TAIL)       { p_bf16 = 0; pbytes = P_F32; }
    else if (ws_size >= P_BF16 + TAIL) { p_bf16 = 1; pbytes = P_BF16; }
    else return;  // impossible workspace -> loud validation failure

    void*               wsp     = (void*)ws;
    unsigned long long* state64 = (unsigned long long*)(ws + pbytes);
    unsigned*           abortf  = (unsigned*)(ws + pbytes + STATE_B);

    // zero tagged state (tag 0 == s_0 valid, value 0.0f) + abort flag
    hipMemsetAsync(ws + pbytes, 0, TAIL, stream);

    dim3 g1(16, 256);
    gemm_in_kernel<<<g1, 256, 0, stream>>>(x, W_in, b_in, out, wsp, p_bf16);
    scan_kernel<<<256, 256, 0, stream>>>(W_s, b_s, wsp, out, state64, abortf, p_bf16);
}